// Round 13
// baseline (97.694 us; speedup 1.0000x reference)
//
#include <hip/hip_runtime.h>

typedef unsigned short u16;
typedef unsigned int u32;
typedef __attribute__((ext_vector_type(8))) __bf16 bf16x8;
typedef __attribute__((ext_vector_type(4))) float f32x4;
typedef __attribute__((ext_vector_type(16))) float f32x16;
typedef __attribute__((ext_vector_type(2))) u16 u16x2;
typedef __attribute__((ext_vector_type(4))) u16 u16x4;
typedef __attribute__((ext_vector_type(4))) u32 u32x4;

#define LOG2E 1.44269504088896f

__device__ __forceinline__ u16 f2bf(float f) {
  unsigned u = __builtin_bit_cast(unsigned, f);
  u += 0x7fffu + ((u >> 16) & 1u);
  return (u16)(u >> 16);
}
__device__ __forceinline__ float bf2f(u16 h) {
  unsigned u = ((unsigned)h) << 16;
  return __builtin_bit_cast(float, u);
}
__device__ __forceinline__ void gload16(void* lds, const void* g) {
  __builtin_amdgcn_global_load_lds(
      (const __attribute__((address_space(1))) void*)g,
      (__attribute__((address_space(3))) void*)lds, 16, 0, 0);
}
__device__ __forceinline__ f32x4 mfma16(bf16x8 a, bf16x8 b, f32x4 c) {
  return __builtin_amdgcn_mfma_f32_16x16x32_bf16(a, b, c, 0, 0, 0);
}
__device__ __forceinline__ f32x16 mfma32(bf16x8 a, bf16x8 b, f32x16 c) {
  return __builtin_amdgcn_mfma_f32_32x32x16_bf16(a, b, c, 0, 0, 0);
}
// native 1-instruction transcendentals (1-ulp, far inside bf16 tolerance)
__device__ __forceinline__ float nexp2(float x) { return __builtin_amdgcn_exp2f(x); }
__device__ __forceinline__ float nrcp(float x) { return __builtin_amdgcn_rcpf(x); }

// Load-balance table: (xcd parity -> 64 ranked (h<<4|qt) items, descending
// per-block iteration count). Slot c pairs with slot 63-c on the same CU.
__device__ __constant__ unsigned char LB_TBL[128] = {
    // group A, ranks 0..63
    0x00,0x10,0x40,0x41,0x70,0x71,0x72,0x73,0x74,0x75,0x76,0x77,0x78,0x79,0x7A,
    0x01,0x11,0x42,0x7B,0x02,0x12,0x43,0x7C,0x03,0x13,0x44,0x7D,0x04,0x14,0x45,
    0x7E,0x05,0x15,0x46,0x7F,0x06,0x16,0x47,0x07,0x17,0x48,0x08,0x18,0x49,0x09,
    0x19,0x4A,0x0A,0x1A,0x4B,0x0B,0x1B,0x4C,0x0C,0x1C,0x4D,0x0D,0x1D,0x4E,0x0E,
    0x1E,0x4F,0x0F,0x1F,
    // group B, ranks 0..63
    0x20,0x30,0x31,0x50,0x51,0x52,0x53,0x60,0x61,0x62,0x63,0x64,0x65,
    0x21,0x32,0x54,0x66,0x22,0x33,0x55,0x67,0x23,0x34,0x56,0x68,0x24,0x35,0x57,
    0x69,0x25,0x36,0x58,0x6A,0x26,0x37,0x59,0x6B,0x27,0x38,0x5A,0x6C,0x28,0x39,
    0x5B,0x6D,0x29,0x3A,0x5C,0x6E,0x2A,0x3B,0x5D,0x6F,0x2B,0x3C,0x5E,0x2C,0x3D,
    0x5F,0x2D,0x3E,0x2E,0x3F,0x2F};

// ---------------- prep: weight converts + sincos (x-convert now fused into
// gemm_bt<2>) -- grid 1280 x 256 ----------------------------------------
__global__ __launch_bounds__(256) void prep_kernel(const float* __restrict__ qkv_w,
                                                   const float* __restrict__ proj_w,
                                                   u16* __restrict__ WQB,
                                                   u16* __restrict__ WPB,
                                                   float* __restrict__ sc) {
  const int bid = blockIdx.x, t = threadIdx.x;
  if (bid < 1024) {
    const float* src;
    u16* dst;
    size_t base;
    if (bid < 768) { src = qkv_w; dst = WQB; base = (size_t)bid; }
    else { src = proj_w; dst = WPB; base = (size_t)(bid - 768); }
    size_t i = base * 256 + t;
    f32x4 v = *(const f32x4*)(src + i * 4);
    u16x4 o;
#pragma unroll
    for (int j = 0; j < 4; ++j) o[j] = f2bf(v[j]);
    *(u16x4*)(dst + i * 4) = o;
  } else {
    int i = (bid - 1024) * 256 + t;  // 2048*32
    int n = i >> 5, d = i & 31;
    float inv = powf(10000.0f, -(float)d * (1.0f / 32.0f));
    float f = (float)n * inv;
    sc[(size_t)n * 64 + d] = sinf(f);
    sc[(size_t)n * 64 + 32 + d] = cosf(f);
  }
}

// ---------------- GEMM C = A @ B^T ----------------------------------------
// 128x128 tile, BK=32, 4 waves, double-buffered prefetch, XCD-clustered grid.
// MODE 0: A bf16 (OB), f32 out + bias (proj), NB=4.
// MODE 2: A = x in f32, staged as f32 tiles (XOR-swizzled, pre-swizzled
//   source per rule #21) and converted to bf16 at fragment load (fuses the
//   x->bf16 convert kernel). Fused RoPE epilogue with pi-interleaved Q/K
//   layout: pair (dlo, dlo+32) stored at (2dlo, 2dlo+1) as one u16x2 ->
//   coalesced 64B stores. Dot products are permutation-invariant; attn
//   consumes the same pi-order in both Q and K. NB=12.
template <int MODE>
__global__ __launch_bounds__(256) void gemm_bt(const u16* __restrict__ A,
                                               const float* __restrict__ Af,
                                               const u16* __restrict__ Bw,
                                               float* __restrict__ Cout,
                                               const float* __restrict__ bias,
                                               const float* __restrict__ SC,
                                               u16* __restrict__ Qo,
                                               u16* __restrict__ Ko,
                                               u16* __restrict__ Vo,
                                               int M, int Nout, int K) {
  // MODE 2: A-tile is f32 (128 rows x 32 f32 = 16KB/buf); MODE 0: bf16 8KB/buf
  __shared__ u16 lA[2][128 * ((MODE == 2) ? 64 : 32)];
  __shared__ u16 lB[2][128 * 32];
  const int t = threadIdx.x;
  const int l = t & 63, w = t >> 6;
  const int lrow = l & 15, lg = l >> 4;
  constexpr int NB = (MODE == 2) ? 12 : 4;
  const int id = blockIdx.x;
  const int xcd = id & 7, kk = id >> 3;
  const int m0 = ((kk / NB) * 8 + xcd) * 128;
  const int n0 = (kk % NB) * 128;
  const int wr = (w >> 1) * 64, wc = (w & 1) * 64;
  f32x4 acc[4][4];
#pragma unroll
  for (int i = 0; i < 4; ++i)
#pragma unroll
    for (int j = 0; j < 4; ++j)
#pragma unroll
      for (int r = 0; r < 4; ++r) acc[i][j][r] = 0.f;

  const int srow = t >> 2;
  const int scb = (t & 3) * 16;
  const int nk = K >> 5;

  auto stageg = [&](int buf, int kt) {
    if constexpr (MODE == 2) {
      // A: 128 rows x 128B f32, 4 passes; XOR-swizzled (row&7)<<4 via source
#pragma unroll
      for (int c = 0; c < 4; ++c) {
        int o = c * 256 + t;  // 0..1023, 16B chunks
        int row = o >> 3;
        int sb = ((o & 7) * 16) ^ ((row & 7) << 4);
        const char* ga =
            (const char*)Af + ((size_t)(m0 + row) * K + kt * 32) * 4 + sb;
        gload16((char*)&lA[buf][0] + o * 16, ga);
      }
    } else {
#pragma unroll
      for (int c = 0; c < 2; ++c) {
        int row = c * 64 + srow;
        const char* ga =
            (const char*)A + ((size_t)(m0 + row) * K + kt * 32) * 2 + scb;
        gload16((char*)&lA[buf][0] + c * 4096 + t * 16, ga);
      }
    }
#pragma unroll
    for (int c = 0; c < 2; ++c) {
      int row = c * 64 + srow;
      const char* gb = (const char*)Bw + ((size_t)(n0 + row) * K + kt * 32) * 2 + scb;
      gload16((char*)&lB[buf][0] + c * 4096 + t * 16, gb);
    }
  };

  stageg(0, 0);
  __syncthreads();
  int cb = 0;
  for (int kt = 0; kt < nk; ++kt) {
    if (kt + 1 < nk) stageg(cb ^ 1, kt + 1);
    bf16x8 af[4], bfr[4];
#pragma unroll
    for (int i = 0; i < 4; ++i) {
      if constexpr (MODE == 2) {
        int arow = wr + i * 16 + lrow;
        int swzr = (arow & 7) << 4;
        const char* ab = (const char*)&lA[cb][0] + arow * 128;
        f32x4 alo = *(const f32x4*)(ab + ((lg * 32) ^ swzr));
        f32x4 ahi = *(const f32x4*)(ab + ((lg * 32 + 16) ^ swzr));
        u32 w0, w1, w2, w3;
        asm("v_cvt_pk_bf16_f32 %0, %1, %2" : "=v"(w0) : "v"(alo[0]), "v"(alo[1]));
        asm("v_cvt_pk_bf16_f32 %0, %1, %2" : "=v"(w1) : "v"(alo[2]), "v"(alo[3]));
        asm("v_cvt_pk_bf16_f32 %0, %1, %2" : "=v"(w2) : "v"(ahi[0]), "v"(ahi[1]));
        asm("v_cvt_pk_bf16_f32 %0, %1, %2" : "=v"(w3) : "v"(ahi[2]), "v"(ahi[3]));
        u32x4 fr;
        fr[0] = w0; fr[1] = w1; fr[2] = w2; fr[3] = w3;
        af[i] = __builtin_bit_cast(bf16x8, fr);
      } else {
        af[i] = *(const bf16x8*)((const char*)&lA[cb][0] +
                                 (wr + i * 16 + lrow) * 64 + lg * 16);
      }
      bfr[i] = *(const bf16x8*)((const char*)&lB[cb][0] + (wc + i * 16 + lrow) * 64 + lg * 16);
    }
#pragma unroll
    for (int i = 0; i < 4; ++i)
#pragma unroll
      for (int j = 0; j < 4; ++j)
        acc[i][j] = mfma16(af[i], bfr[j], acc[i][j]);
    __syncthreads();
    cb ^= 1;
  }

  if constexpr (MODE == 0) {
#pragma unroll
    for (int i = 0; i < 4; ++i)
#pragma unroll
      for (int j = 0; j < 4; ++j)
#pragma unroll
        for (int r = 0; r < 4; ++r) {
          int m = m0 + wr + i * 16 + lg * 4 + r;
          int n = n0 + wc + j * 16 + lrow;
          Cout[(size_t)m * Nout + n] = acc[i][j][r] + bias[n];
        }
  } else {
    const int part = n0 >> 9;
    if (part < 2) {
      u16* Dst = (part == 0) ? Qo : Ko;
      const int hh = ((n0 & 511) + wc) >> 6;
#pragma unroll
      for (int i = 0; i < 4; ++i) {
#pragma unroll
        for (int r = 0; r < 4; ++r) {
          int m = m0 + wr + i * 16 + lg * 4 + r;
          int bb = m >> 11, nseq = m & 2047;
          const float* scrow = SC + (size_t)nseq * 64;
          u16* orow = Dst + ((size_t)(bb * 8 + hh) * 2048 + nseq) * 64;
#pragma unroll
          for (int j = 0; j < 2; ++j) {
            int dlo = j * 16 + lrow;
            float s = scrow[dlo], c = scrow[32 + dlo];
            float v1 = acc[i][j][r], v2 = acc[i][j + 2][r];
            u16x2 pr;
            pr[0] = f2bf(v1 * c - v2 * s);
            pr[1] = f2bf(v2 * c + v1 * s);
            *(u16x2*)(orow + 2 * dlo) = pr;  // pi-interleaved, coalesced
          }
        }
      }
    } else {
#pragma unroll
      for (int i = 0; i < 4; ++i) {
        int m = m0 + wr + i * 16 + lg * 4;
        int bb = m >> 11, nseq = m & 2047;
#pragma unroll
        for (int j = 0; j < 4; ++j) {
          int pc = (n0 & 511) + wc + j * 16 + lrow;
          int hh = pc >> 6, d = pc & 63;
          u16x4 pk;
#pragma unroll
          for (int r = 0; r < 4; ++r) pk[r] = f2bf(acc[i][j][r]);
          *(u16x4*)(Vo + ((size_t)((bb * 8 + hh) * 64 + d)) * 2048 + nseq) = pk;
        }
      }
    }
  }
}

// ---------------- flash attention, ALiBi, dynamic-window split-KV ---------
// FROZEN: R9-measured-good kernel (43.4 us). Q/K now arrive pi-interleaved
// (pair (dlo,dlo+32) at u16 (2dlo,2dlo+1)) -- consistent in both operands of
// QK^T, so no change here (dot products permutation-invariant).
__global__ __launch_bounds__(512, 4) void attn_kernel(const u16* __restrict__ Q,
                                                      const u16* __restrict__ Kn,
                                                      const u16* __restrict__ Vt,
                                                      u16* __restrict__ Ob) {
  __shared__ u16 KV[2][2][2][4096];  // [buf][half][K/V][64 rows x 128B] = 64KB
  const int t = threadIdx.x, l = t & 63, w = t >> 6;
  const int li = l & 31, hi = l >> 5;
  const int half = w >> 2, g = w & 3;

  // table-driven placement
  const int id = blockIdx.x + 32 * blockIdx.y;
  const int xcd = id & 7, slot = id >> 3;
  const int rank = slot < 32 ? slot : 95 - slot;
  const int item = LB_TBL[(xcd & 1) * 64 + rank];
  const int h = item >> 4, qt = item & 15;
  const int bh = (xcd >> 1) * 8 + h;
  const int b = xcd >> 1;

  const int qg = qt * 128 + g * 32 + li;            // this lane's query
  const float sl2 = nexp2((float)(2 - h)) * LOG2E;  // MAX_BIAS*slope*log2e
  const float sc2 = 0.125f * LOG2E;                 // scale*log2e
  const int swz = (li & 7) << 4;

  // dynamic active range (block-uniform)
  const int wint = (int)(10.3974f * (float)(1 << h));  // 60/sl2 window keys
  int lo_i = 128 * qt + 64 - wint;
  const int lo = lo_i <= 0 ? 0 : (lo_i & ~63);
  const int T = (2048 - lo) >> 6;
  const int nIter = (T + 1) >> 1;

  // Q fragments: qa[s] = Q[qg][pi-d = s*16 + hi*8 + 0..7]
  bf16x8 qa[4];
  {
    const char* qb = (const char*)Q + ((size_t)bh * 2048 + qg) * 128 + hi * 16;
#pragma unroll
    for (int s = 0; s < 4; ++s) qa[s] = *(const bf16x8*)(qb + s * 32);
  }
  // ALiBi: key = k0 + kb*32 + 8*(r>>2) + (r&3) + 4*hi
  float cst[4];
#pragma unroll
  for (int j = 0; j < 4; ++j) cst[j] = (float)j * sl2;
  const float c8 = 8.f * sl2, c32 = 32.f * sl2;
  float vbm = (float)(4 * hi - qg) * sl2;  // (4hi - qg)*sl2 - shift (shift=0)
  float negm = 0.f;                        // -shift
  float lrun = 0.f;
  f32x16 oacc0, oacc1;
#pragma unroll
  for (int r = 0; r < 16; ++r) { oacc0[r] = 0.f; oacc1[r] = 0.f; }

  // stage both halves' tiles for iteration it: 32KB, 512 thr x 4 x 16B
  auto stage = [&](int buf, int it) {
#pragma unroll
    for (int c = 0; c < 4; ++c) {
      int o = c * 512 + t;               // chunk 0..2047
      int half_s = o >> 10, rem = o & 1023;
      int kv = rem >> 9, idx = rem & 511;
      int row = idx >> 3;
      int sb = ((idx & 7) * 16) ^ ((row & 7) << 4);
      int k0s = lo + (half_s ? nIter + it : it) * 64;
      if (k0s < 2048) {
        char* dst = (char*)KV + buf * 32768 + half_s * 16384 + kv * 8192 + idx * 16;
        const char* src;
        if (kv == 0)
          src = (const char*)Kn + ((size_t)(bh * 2048 + k0s + row)) * 128 + sb;
        else
          src = (const char*)Vt + ((size_t)(bh * 64 + row)) * 4096 +
                (size_t)k0s * 2 + sb;
        gload16(dst, src);
      }
    }
  };

  stage(0, 0);
  __syncthreads();
  int cur = 0;
  const char* myK = (const char*)KV + half * 16384;
  const char* myV = myK + 8192;
  for (int it = 0; it < nIter; ++it) {
    if (it + 1 < nIter) stage(cur ^ 1, it + 1);  // prefetch next tile pair

    const int k0g = lo + (half ? nIter + it : it) * 64;
    const bool active = (k0g < 2048);  // wave-uniform (odd-T tail only)
    if (active) {
      const float basem0 = fmaf((float)k0g, sl2, vbm);

      // ---- per-kb: S' = K Q^T -> bias -> exp2 -> P-frag (16 live) ----
      float ls0 = 0.f, ls1 = 0.f;
      bf16x8 pf[4];
#pragma unroll
      for (int kb = 0; kb < 2; ++kb) {
        f32x16 sa;
#pragma unroll
        for (int r = 0; r < 16; ++r) sa[r] = 0.f;
        const char* kb_base = myK + cur * 32768 + kb * 4096 + li * 128;
        __builtin_amdgcn_s_setprio(1);
#pragma unroll
        for (int s = 0; s < 4; ++s) {
          bf16x8 kf = *(const bf16x8*)(kb_base + ((s * 32 + hi * 16) ^ swz));
          sa = mfma32(kf, qa[s], sa);
        }
        __builtin_amdgcn_s_setprio(0);
        float bq[4];
        bq[0] = kb ? basem0 + c32 : basem0;
        bq[1] = bq[0] + c8;
        bq[2] = bq[1] + c8;
        bq[3] = bq[2] + c8;
        float p[16];
#pragma unroll
        for (int r = 0; r < 16; ++r)
          p[r] = fmaf(sa[r], sc2, fminf(bq[r >> 2] + cst[r & 3], negm));
#pragma unroll
        for (int r = 0; r < 16; r += 2) {
          float e0 = nexp2(p[r]), e1 = nexp2(p[r + 1]);
          p[r] = e0;
          p[r + 1] = e1;
          ls0 += e0;
          ls1 += e1;
        }
        // P -> bf16 A-fragments via cvt_pk + permlane32_swap (T12)
#pragma unroll
        for (int s = 0; s < 2; ++s) {
          u32 a0, b0, a1, b1;
          asm("v_cvt_pk_bf16_f32 %0, %1, %2" : "=v"(a0) : "v"(p[s * 8 + 0]), "v"(p[s * 8 + 1]));
          asm("v_cvt_pk_bf16_f32 %0, %1, %2" : "=v"(b0) : "v"(p[s * 8 + 4]), "v"(p[s * 8 + 5]));
          asm("v_cvt_pk_bf16_f32 %0, %1, %2" : "=v"(a1) : "v"(p[s * 8 + 2]), "v"(p[s * 8 + 3]));
          asm("v_cvt_pk_bf16_f32 %0, %1, %2" : "=v"(b1) : "v"(p[s * 8 + 6]), "v"(p[s * 8 + 7]));
          asm("v_permlane32_swap_b32 %0, %1" : "+v"(a0), "+v"(b0));
          asm("v_permlane32_swap_b32 %0, %1" : "+v"(a1), "+v"(b1));
          u32x4 fr;
          fr[0] = a0; fr[1] = a1; fr[2] = b0; fr[3] = b1;
          pf[kb * 2 + s] = __builtin_bit_cast(bf16x8, fr);
        }
      }
      float ls = ls0 + ls1;
      ls += __shfl_xor(ls, 32);
      lrun += ls;

      // ---- O' += Vt P^T (2 d-blocks x 4 k-steps) ----
      const char* vb_base = myV + cur * 32768 + li * 128;
      __builtin_amdgcn_s_setprio(1);
#pragma unroll
      for (int ks = 0; ks < 4; ++ks) {
        int off = (ks * 32 + hi * 16) ^ swz;
        bf16x8 vf0 = *(const bf16x8*)(vb_base + off);
        bf16x8 vf1 = *(const bf16x8*)(vb_base + 4096 + off);
        oacc0 = mfma32(vf0, pf[ks], oacc0);
        oacc1 = mfma32(vf1, pf[ks], oacc1);
      }
      __builtin_amdgcn_s_setprio(0);

      // overflow guard (never taken for this data; exact shift if it fires)
      if (__any(lrun > 1e28f)) {
        vbm -= 64.f;
        negm -= 64.f;
        lrun *= 0x1p-64f;
#pragma unroll
        for (int r = 0; r < 16; ++r) {
          oacc0[r] *= 0x1p-64f;
          oacc1[r] *= 0x1p-64f;
        }
      }
    }
    __syncthreads();
    cur ^= 1;
  }

  // ---- merge halves: wave w+4 publishes, wave w combines ----
  float* S = (float*)KV;  // reuse staging LDS: [g][34][64] f32
  if (half == 1) {
    float* base = S + (size_t)g * 34 * 64;
#pragma unroll
    for (int r = 0; r < 16; ++r) {
      base[r * 64 + l] = oacc0[r];
      base[(16 + r) * 64 + l] = oacc1[r];
    }
    base[32 * 64 + l] = lrun;
    base[33 * 64 + l] = negm;
  }
  __syncthreads();
  if (half == 0) {
    const float* base = S + (size_t)g * 34 * 64;
    float lB = base[32 * 64 + l];
    float negmB = base[33 * 64 + l];
    float mA = -negm, mB = -negmB;
    float mS = fmaxf(mA, mB);
    float aA = nexp2(mA - mS), aB = nexp2(mB - mS);
    float linv = nrcp(fmaf(lrun, aA, lB * aB));
    float cA = aA * linv, cB = aB * linv;
    u16* orow = Ob + ((size_t)b * 2048 + qg) * 512 + h * 64;
#pragma unroll
    for (int db = 0; db < 2; ++db) {
#pragma unroll
      for (int gg = 0; gg < 4; ++gg) {
        u16x4 pk;
#pragma unroll
        for (int j = 0; j < 4; ++j) {
          int r = gg * 4 + j;
          float oA = db ? oacc1[r] : oacc0[r];
          float oB = base[(db * 16 + r) * 64 + l];
          pk[j] = f2bf(oA * cA + oB * cB);
        }
        *(u16x4*)(orow + db * 32 + gg * 8 + 4 * hi) = pk;
      }
    }
  }
}

// ---------------- launch ---------------------------------------------------
extern "C" void kernel_launch(void* const* d_in, const int* in_sizes, int n_in,
                              void* d_out, int out_size, void* d_ws, size_t ws_size,
                              hipStream_t stream) {
  const float* x = (const float*)d_in[0];
  const float* qkv_w = (const float*)d_in[1];
  const float* proj_w = (const float*)d_in[2];
  const float* proj_b = (const float*)d_in[3];
  char* ws = (char*)d_ws;

  u16* WQB = (u16*)(ws + 0);            // 1536x512 bf16 (qkv_w)
  u16* WPB = (u16*)(ws + 1572864);      // 512x512 bf16 (proj_w)
  u16* QB = (u16*)(ws + 2097152);       // [32][2048][64] (roped q, pi-order)
  u16* KB = (u16*)(ws + 10485760);      // [32][2048][64] (roped k, pi-order)
  u16* VTB = (u16*)(ws + 18874368);     // [32][64][2048] (v transposed)
  u16* OB = (u16*)(ws + 27262976);      // 8192x512 bf16 (attn out)
  float* SC = (float*)(ws + 35651584);  // 2048x64 f32 sin/cos

  prep_kernel<<<1280, 256, 0, stream>>>(qkv_w, proj_w, WQB, WPB, SC);
  gemm_bt<2><<<768, 256, 0, stream>>>(nullptr, x, WQB, nullptr, nullptr, SC, QB,
                                      KB, VTB, 8192, 1536, 512);
  attn_kernel<<<dim3(32, 16), 512, 0, stream>>>(QB, KB, VTB, OB);
  gemm_bt<0><<<256, 256, 0, stream>>>(OB, nullptr, WPB, (float*)d_out, proj_b,
                                      nullptr, nullptr, nullptr, nullptr,
                                      8192, 512, 512);
}

// Round 14
// 85.170 us; speedup vs baseline: 1.1470x; 1.1470x over previous
//
#include <hip/hip_runtime.h>

typedef unsigned short u16;
typedef unsigned int u32;
typedef __attribute__((ext_vector_type(8))) __bf16 bf16x8;
typedef __attribute__((ext_vector_type(4))) float f32x4;
typedef __attribute__((ext_vector_type(16))) float f32x16;
typedef __attribute__((ext_vector_type(4))) u16 u16x4;
typedef __attribute__((ext_vector_type(4))) u32 u32x4;

#define LOG2E 1.44269504088896f

__device__ __forceinline__ u16 f2bf(float f) {
  unsigned u = __builtin_bit_cast(unsigned, f);
  u += 0x7fffu + ((u >> 16) & 1u);
  return (u16)(u >> 16);
}
__device__ __forceinline__ float bf2f(u16 h) {
  unsigned u = ((unsigned)h) << 16;
  return __builtin_bit_cast(float, u);
}
__device__ __forceinline__ void gload16(void* lds, const void* g) {
  __builtin_amdgcn_global_load_lds(
      (const __attribute__((address_space(1))) void*)g,
      (__attribute__((address_space(3))) void*)lds, 16, 0, 0);
}
__device__ __forceinline__ f32x4 mfma16(bf16x8 a, bf16x8 b, f32x4 c) {
  return __builtin_amdgcn_mfma_f32_16x16x32_bf16(a, b, c, 0, 0, 0);
}
__device__ __forceinline__ f32x16 mfma32(bf16x8 a, bf16x8 b, f32x16 c) {
  return __builtin_amdgcn_mfma_f32_32x32x16_bf16(a, b, c, 0, 0, 0);
}
// native 1-instruction transcendentals (exp2f/1.0f/x go through OCML's
// multi-instruction guarded sequences without fast-math; v_exp_f32/v_rcp_f32
// are 1-ulp -- far inside the bf16 tolerance)
__device__ __forceinline__ float nexp2(float x) { return __builtin_amdgcn_exp2f(x); }
__device__ __forceinline__ float nrcp(float x) { return __builtin_amdgcn_rcpf(x); }

// Load-balance table: (xcd parity -> 64 ranked (h<<4|qt) items, descending
// per-block iteration count). Slot c pairs with slot 63-c on the same CU.
__device__ __constant__ unsigned char LB_TBL[128] = {
    // group A, ranks 0..63
    0x00,0x10,0x40,0x41,0x70,0x71,0x72,0x73,0x74,0x75,0x76,0x77,0x78,0x79,0x7A,
    0x01,0x11,0x42,0x7B,0x02,0x12,0x43,0x7C,0x03,0x13,0x44,0x7D,0x04,0x14,0x45,
    0x7E,0x05,0x15,0x46,0x7F,0x06,0x16,0x47,0x07,0x17,0x48,0x08,0x18,0x49,0x09,
    0x19,0x4A,0x0A,0x1A,0x4B,0x0B,0x1B,0x4C,0x0C,0x1C,0x4D,0x0D,0x1D,0x4E,0x0E,
    0x1E,0x4F,0x0F,0x1F,
    // group B, ranks 0..63
    0x20,0x30,0x31,0x50,0x51,0x52,0x53,0x60,0x61,0x62,0x63,0x64,0x65,
    0x21,0x32,0x54,0x66,0x22,0x33,0x55,0x67,0x23,0x34,0x56,0x68,0x24,0x35,0x57,
    0x69,0x25,0x36,0x58,0x6A,0x26,0x37,0x59,0x6B,0x27,0x38,0x5A,0x6C,0x28,0x39,
    0x5B,0x6D,0x29,0x3A,0x5C,0x6E,0x2A,0x3B,0x5D,0x6F,0x2B,0x3C,0x5E,0x2C,0x3D,
    0x5F,0x2D,0x3E,0x2E,0x3F,0x2F};

// ---------------- fused prep: converts (x, qkv_w, proj_w) + sincos --------
__global__ __launch_bounds__(256) void prep_kernel(const float* __restrict__ x,
                                                   const float* __restrict__ qkv_w,
                                                   const float* __restrict__ proj_w,
                                                   u16* __restrict__ XB,
                                                   u16* __restrict__ WQB,
                                                   u16* __restrict__ WPB,
                                                   float* __restrict__ sc) {
  const int bid = blockIdx.x, t = threadIdx.x;
  if (bid < 5120) {
    const float* src;
    u16* dst;
    size_t base;
    if (bid < 4096) { src = x; dst = XB; base = (size_t)bid; }
    else if (bid < 4864) { src = qkv_w; dst = WQB; base = (size_t)(bid - 4096); }
    else { src = proj_w; dst = WPB; base = (size_t)(bid - 4864); }
    size_t i = base * 256 + t;
    f32x4 v = *(const f32x4*)(src + i * 4);
    u16x4 o;
#pragma unroll
    for (int j = 0; j < 4; ++j) o[j] = f2bf(v[j]);
    *(u16x4*)(dst + i * 4) = o;
  } else {
    int i = (bid - 5120) * 256 + t;  // 2048*32
    int n = i >> 5, d = i & 31;
    float inv = powf(10000.0f, -(float)d * (1.0f / 32.0f));
    float f = (float)n * inv;
    sc[(size_t)n * 64 + d] = sinf(f);
    sc[(size_t)n * 64 + 32 + d] = cosf(f);
  }
}

// ---------------- GEMM C = A @ B^T (both row-major, K contiguous) ----------
// BK=32, 4 waves, double-buffered prefetch, XCD-clustered 1D grid.
// MODE 2: 128x128 tile, NB=12, fused RoPE epilogue (natural Q/K layout).
// MODE 0: 128x64 tile, NB=8 -> 512 blocks = 2 blocks/CU (proj was
//   latency-bound at 1 block/CU, 12.5% occupancy); f32 out + bias.
template <int MODE>
__global__ __launch_bounds__(256) void gemm_bt(const u16* __restrict__ A,
                                               const u16* __restrict__ Bw,
                                               float* __restrict__ Cout,
                                               const float* __restrict__ bias,
                                               const float* __restrict__ SC,
                                               u16* __restrict__ Qo,
                                               u16* __restrict__ Ko,
                                               u16* __restrict__ Vo,
                                               int M, int Nout, int K) {
  constexpr int NB = (MODE == 2) ? 12 : 8;    // N-blocks per M-panel
  constexpr int BN = (MODE == 2) ? 128 : 64;  // tile N
  constexpr int NJ = BN / 32;                 // per-wave j-frags (4 or 2)
  __shared__ u16 lA[2][128 * 32];
  __shared__ u16 lB[2][BN * 32];
  const int t = threadIdx.x;
  const int l = t & 63, w = t >> 6;
  const int lrow = l & 15, lg = l >> 4;
  const int id = blockIdx.x;
  const int xcd = id & 7, kk = id >> 3;
  const int m0 = ((kk / NB) * 8 + xcd) * 128;
  const int n0 = (kk % NB) * BN;
  const int wr = (w >> 1) * 64, wc = (w & 1) * (BN / 2);
  f32x4 acc[4][NJ];
#pragma unroll
  for (int i = 0; i < 4; ++i)
#pragma unroll
    for (int j = 0; j < NJ; ++j)
#pragma unroll
      for (int r = 0; r < 4; ++r) acc[i][j][r] = 0.f;

  const int srow = t >> 2;
  const int scb = (t & 3) * 16;
  const int nk = K >> 5;

  auto stageg = [&](int buf, int kt) {
#pragma unroll
    for (int c = 0; c < 2; ++c) {
      int row = c * 64 + srow;
      const char* ga = (const char*)A + ((size_t)(m0 + row) * K + kt * 32) * 2 + scb;
      gload16((char*)&lA[buf][0] + c * 4096 + t * 16, ga);
    }
#pragma unroll
    for (int c = 0; c < BN / 64; ++c) {
      int row = c * 64 + srow;
      const char* gb = (const char*)Bw + ((size_t)(n0 + row) * K + kt * 32) * 2 + scb;
      gload16((char*)&lB[buf][0] + c * 4096 + t * 16, gb);
    }
  };

  stageg(0, 0);
  __syncthreads();
  int cb = 0;
  for (int kt = 0; kt < nk; ++kt) {
    if (kt + 1 < nk) stageg(cb ^ 1, kt + 1);
    bf16x8 af[4], bfr[NJ];
#pragma unroll
    for (int i = 0; i < 4; ++i)
      af[i] = *(const bf16x8*)((const char*)&lA[cb][0] + (wr + i * 16 + lrow) * 64 + lg * 16);
#pragma unroll
    for (int j = 0; j < NJ; ++j)
      bfr[j] = *(const bf16x8*)((const char*)&lB[cb][0] + (wc + j * 16 + lrow) * 64 + lg * 16);
#pragma unroll
    for (int i = 0; i < 4; ++i)
#pragma unroll
      for (int j = 0; j < NJ; ++j)
        acc[i][j] = mfma16(af[i], bfr[j], acc[i][j]);
    __syncthreads();
    cb ^= 1;
  }

  if constexpr (MODE == 0) {
#pragma unroll
    for (int i = 0; i < 4; ++i)
#pragma unroll
      for (int j = 0; j < NJ; ++j)
#pragma unroll
        for (int r = 0; r < 4; ++r) {
          int m = m0 + wr + i * 16 + lg * 4 + r;
          int n = n0 + wc + j * 16 + lrow;
          Cout[(size_t)m * Nout + n] = acc[i][j][r] + bias[n];
        }
  } else {
    const int part = n0 >> 9;
    if (part < 2) {
      u16* Dst = (part == 0) ? Qo : Ko;
      const int hh = ((n0 & 511) + wc) >> 6;
#pragma unroll
      for (int i = 0; i < 4; ++i) {
#pragma unroll
        for (int r = 0; r < 4; ++r) {
          int m = m0 + wr + i * 16 + lg * 4 + r;
          int bb = m >> 11, nseq = m & 2047;
          const float* scrow = SC + (size_t)nseq * 64;
          u16* orow = Dst + ((size_t)(bb * 8 + hh) * 2048 + nseq) * 64;
#pragma unroll
          for (int j = 0; j < 2; ++j) {
            int dlo = j * 16 + lrow;
            float s = scrow[dlo], c = scrow[32 + dlo];
            float v1 = acc[i][j][r], v2 = acc[i][j + 2][r];
            orow[dlo] = f2bf(v1 * c - v2 * s);
            orow[dlo + 32] = f2bf(v2 * c + v1 * s);
          }
        }
      }
    } else {
#pragma unroll
      for (int i = 0; i < 4; ++i) {
        int m = m0 + wr + i * 16 + lg * 4;
        int bb = m >> 11, nseq = m & 2047;
#pragma unroll
        for (int j = 0; j < 4; ++j) {
          int pc = (n0 & 511) + wc + j * 16 + lrow;
          int hh = pc >> 6, d = pc & 63;
          u16x4 pk;
#pragma unroll
          for (int r = 0; r < 4; ++r) pk[r] = f2bf(acc[i][j][r]);
          *(u16x4*)(Vo + ((size_t)((bb * 8 + hh) * 64 + d)) * 2048 + nseq) = pk;
        }
      }
    }
  }
}

// ---------------- flash attention, ALiBi, dynamic-window split-KV ---------
// FROZEN: R9/R12-measured-good kernel (43.4 us). Do not add loop-carried
// pointer state or branchy bias paths (both spilled at the (512,4) cap).
__global__ __launch_bounds__(512, 4) void attn_kernel(const u16* __restrict__ Q,
                                                      const u16* __restrict__ Kn,
                                                      const u16* __restrict__ Vt,
                                                      u16* __restrict__ Ob) {
  __shared__ u16 KV[2][2][2][4096];  // [buf][half][K/V][64 rows x 128B] = 64KB
  const int t = threadIdx.x, l = t & 63, w = t >> 6;
  const int li = l & 31, hi = l >> 5;
  const int half = w >> 2, g = w & 3;

  // table-driven placement
  const int id = blockIdx.x + 32 * blockIdx.y;
  const int xcd = id & 7, slot = id >> 3;
  const int rank = slot < 32 ? slot : 95 - slot;
  const int item = LB_TBL[(xcd & 1) * 64 + rank];
  const int h = item >> 4, qt = item & 15;
  const int bh = (xcd >> 1) * 8 + h;
  const int b = xcd >> 1;

  const int qg = qt * 128 + g * 32 + li;            // this lane's query
  const float sl2 = nexp2((float)(2 - h)) * LOG2E;  // MAX_BIAS*slope*log2e
  const float sc2 = 0.125f * LOG2E;                 // scale*log2e
  const int swz = (li & 7) << 4;

  // dynamic active range (block-uniform)
  const int wint = (int)(10.3974f * (float)(1 << h));  // 60/sl2 window keys
  int lo_i = 128 * qt + 64 - wint;
  const int lo = lo_i <= 0 ? 0 : (lo_i & ~63);
  const int T = (2048 - lo) >> 6;
  const int nIter = (T + 1) >> 1;

  // Q fragments: qa[s] = Q[qg][d = s*16 + hi*8 + 0..7]
  bf16x8 qa[4];
  {
    const char* qb = (const char*)Q + ((size_t)bh * 2048 + qg) * 128 + hi * 16;
#pragma unroll
    for (int s = 0; s < 4; ++s) qa[s] = *(const bf16x8*)(qb + s * 32);
  }
  // ALiBi: key = k0 + kb*32 + 8*(r>>2) + (r&3) + 4*hi
  float cst[4];
#pragma unroll
  for (int j = 0; j < 4; ++j) cst[j] = (float)j * sl2;
  const float c8 = 8.f * sl2, c32 = 32.f * sl2;
  float vbm = (float)(4 * hi - qg) * sl2;  // (4hi - qg)*sl2 - shift (shift=0)
  float negm = 0.f;                        // -shift
  float lrun = 0.f;
  f32x16 oacc0, oacc1;
#pragma unroll
  for (int r = 0; r < 16; ++r) { oacc0[r] = 0.f; oacc1[r] = 0.f; }

  // stage both halves' tiles for iteration it: 32KB, 512 thr x 4 x 16B
  auto stage = [&](int buf, int it) {
#pragma unroll
    for (int c = 0; c < 4; ++c) {
      int o = c * 512 + t;               // chunk 0..2047
      int half_s = o >> 10, rem = o & 1023;
      int kv = rem >> 9, idx = rem & 511;
      int row = idx >> 3;
      int sb = ((idx & 7) * 16) ^ ((row & 7) << 4);
      int k0s = lo + (half_s ? nIter + it : it) * 64;
      if (k0s < 2048) {
        char* dst = (char*)KV + buf * 32768 + half_s * 16384 + kv * 8192 + idx * 16;
        const char* src;
        if (kv == 0)
          src = (const char*)Kn + ((size_t)(bh * 2048 + k0s + row)) * 128 + sb;
        else
          src = (const char*)Vt + ((size_t)(bh * 64 + row)) * 4096 +
                (size_t)k0s * 2 + sb;
        gload16(dst, src);
      }
    }
  };

  stage(0, 0);
  __syncthreads();
  int cur = 0;
  const char* myK = (const char*)KV + half * 16384;
  const char* myV = myK + 8192;
  for (int it = 0; it < nIter; ++it) {
    if (it + 1 < nIter) stage(cur ^ 1, it + 1);  // prefetch next tile pair

    const int k0g = lo + (half ? nIter + it : it) * 64;
    const bool active = (k0g < 2048);  // wave-uniform (odd-T tail only)
    if (active) {
      const float basem0 = fmaf((float)k0g, sl2, vbm);

      // ---- per-kb: S' = K Q^T -> bias -> exp2 -> P-frag (16 live) ----
      float ls0 = 0.f, ls1 = 0.f;
      bf16x8 pf[4];
#pragma unroll
      for (int kb = 0; kb < 2; ++kb) {
        f32x16 sa;
#pragma unroll
        for (int r = 0; r < 16; ++r) sa[r] = 0.f;
        const char* kb_base = myK + cur * 32768 + kb * 4096 + li * 128;
        __builtin_amdgcn_s_setprio(1);
#pragma unroll
        for (int s = 0; s < 4; ++s) {
          bf16x8 kf = *(const bf16x8*)(kb_base + ((s * 32 + hi * 16) ^ swz));
          sa = mfma32(kf, qa[s], sa);
        }
        __builtin_amdgcn_s_setprio(0);
        float bq[4];
        bq[0] = kb ? basem0 + c32 : basem0;
        bq[1] = bq[0] + c8;
        bq[2] = bq[1] + c8;
        bq[3] = bq[2] + c8;
        float p[16];
#pragma unroll
        for (int r = 0; r < 16; ++r)
          p[r] = fmaf(sa[r], sc2, fminf(bq[r >> 2] + cst[r & 3], negm));
#pragma unroll
        for (int r = 0; r < 16; r += 2) {
          float e0 = nexp2(p[r]), e1 = nexp2(p[r + 1]);
          p[r] = e0;
          p[r + 1] = e1;
          ls0 += e0;
          ls1 += e1;
        }
        // P -> bf16 A-fragments via cvt_pk + permlane32_swap (T12)
#pragma unroll
        for (int s = 0; s < 2; ++s) {
          u32 a0, b0, a1, b1;
          asm("v_cvt_pk_bf16_f32 %0, %1, %2" : "=v"(a0) : "v"(p[s * 8 + 0]), "v"(p[s * 8 + 1]));
          asm("v_cvt_pk_bf16_f32 %0, %1, %2" : "=v"(b0) : "v"(p[s * 8 + 4]), "v"(p[s * 8 + 5]));
          asm("v_cvt_pk_bf16_f32 %0, %1, %2" : "=v"(a1) : "v"(p[s * 8 + 2]), "v"(p[s * 8 + 3]));
          asm("v_cvt_pk_bf16_f32 %0, %1, %2" : "=v"(b1) : "v"(p[s * 8 + 6]), "v"(p[s * 8 + 7]));
          asm("v_permlane32_swap_b32 %0, %1" : "+v"(a0), "+v"(b0));
          asm("v_permlane32_swap_b32 %0, %1" : "+v"(a1), "+v"(b1));
          u32x4 fr;
          fr[0] = a0; fr[1] = a1; fr[2] = b0; fr[3] = b1;
          pf[kb * 2 + s] = __builtin_bit_cast(bf16x8, fr);
        }
      }
      float ls = ls0 + ls1;
      ls += __shfl_xor(ls, 32);
      lrun += ls;

      // ---- O' += Vt P^T (2 d-blocks x 4 k-steps) ----
      const char* vb_base = myV + cur * 32768 + li * 128;
      __builtin_amdgcn_s_setprio(1);
#pragma unroll
      for (int ks = 0; ks < 4; ++ks) {
        int off = (ks * 32 + hi * 16) ^ swz;
        bf16x8 vf0 = *(const bf16x8*)(vb_base + off);
        bf16x8 vf1 = *(const bf16x8*)(vb_base + 4096 + off);
        oacc0 = mfma32(vf0, pf[ks], oacc0);
        oacc1 = mfma32(vf1, pf[ks], oacc1);
      }
      __builtin_amdgcn_s_setprio(0);

      // overflow guard (never taken for this data; exact shift if it fires)
      if (__any(lrun > 1e28f)) {
        vbm -= 64.f;
        negm -= 64.f;
        lrun *= 0x1p-64f;
#pragma unroll
        for (int r = 0; r < 16; ++r) {
          oacc0[r] *= 0x1p-64f;
          oacc1[r] *= 0x1p-64f;
        }
      }
    }
    __syncthreads();
    cur ^= 1;
  }

  // ---- merge halves: wave w+4 publishes, wave w combines ----
  float* S = (float*)KV;  // reuse staging LDS: [g][34][64] f32
  if (half == 1) {
    float* base = S + (size_t)g * 34 * 64;
#pragma unroll
    for (int r = 0; r < 16; ++r) {
      base[r * 64 + l] = oacc0[r];
      base[(16 + r) * 64 + l] = oacc1[r];
    }
    base[32 * 64 + l] = lrun;
    base[33 * 64 + l] = negm;
  }
  __syncthreads();
  if (half == 0) {
    const float* base = S + (size_t)g * 34 * 64;
    float lB = base[32 * 64 + l];
    float negmB = base[33 * 64 + l];
    float mA = -negm, mB = -negmB;
    float mS = fmaxf(mA, mB);
    float aA = nexp2(mA - mS), aB = nexp2(mB - mS);
    float linv = nrcp(fmaf(lrun, aA, lB * aB));
    float cA = aA * linv, cB = aB * linv;
    u16* orow = Ob + ((size_t)b * 2048 + qg) * 512 + h * 64;
#pragma unroll
    for (int db = 0; db < 2; ++db) {
#pragma unroll
      for (int gg = 0; gg < 4; ++gg) {
        u16x4 pk;
#pragma unroll
        for (int j = 0; j < 4; ++j) {
          int r = gg * 4 + j;
          float oA = db ? oacc1[r] : oacc0[r];
          float oB = base[(db * 16 + r) * 64 + l];
          pk[j] = f2bf(oA * cA + oB * cB);
        }
        *(u16x4*)(orow + db * 32 + gg * 8 + 4 * hi) = pk;
      }
    }
  }
}

// ---------------- launch ---------------------------------------------------
extern "C" void kernel_launch(void* const* d_in, const int* in_sizes, int n_in,
                              void* d_out, int out_size, void* d_ws, size_t ws_size,
                              hipStream_t stream) {
  const float* x = (const float*)d_in[0];
  const float* qkv_w = (const float*)d_in[1];
  const float* proj_w = (const float*)d_in[2];
  const float* proj_b = (const float*)d_in[3];
  char* ws = (char*)d_ws;

  u16* XB = (u16*)(ws + 0);             // 8192x512 bf16 (x)
  u16* WQB = (u16*)(ws + 8388608);      // 1536x512 bf16 (qkv_w)
  u16* WPB = (u16*)(ws + 9961472);      // 512x512 bf16 (proj_w)
  u16* QB = (u16*)(ws + 10485760);      // [32][2048][64] (roped q)
  u16* KB = (u16*)(ws + 18874368);      // [32][2048][64] (roped k)
  u16* VTB = (u16*)(ws + 27262976);     // [32][64][2048] (v transposed)
  u16* OB = (u16*)(ws + 35651584);      // 8192x512 bf16 (attn out)
  float* SC = (float*)(ws + 44040192);  // 2048x64 f32 sin/cos

  prep_kernel<<<5376, 256, 0, stream>>>(x, qkv_w, proj_w, XB, WQB, WPB, SC);
  gemm_bt<2><<<768, 256, 0, stream>>>(XB, WQB, nullptr, nullptr, SC, QB,
                                      KB, VTB, 8192, 1536, 512);
  attn_kernel<<<dim3(32, 16), 512, 0, stream>>>(QB, KB, VTB, OB);
  gemm_bt<0><<<512, 256, 0, stream>>>(OB, WPB, (float*)d_out, proj_b,
                                      nullptr, nullptr, nullptr, nullptr,
                                      8192, 512, 512);
}

// Round 15
// 84.854 us; speedup vs baseline: 1.1513x; 1.0037x over previous
//
#include <hip/hip_runtime.h>

typedef unsigned short u16;
typedef unsigned int u32;
typedef __attribute__((ext_vector_type(8))) __bf16 bf16x8;
typedef __attribute__((ext_vector_type(4))) float f32x4;
typedef __attribute__((ext_vector_type(16))) float f32x16;
typedef __attribute__((ext_vector_type(4))) u16 u16x4;
typedef __attribute__((ext_vector_type(4))) u32 u32x4;

#define LOG2E 1.44269504088896f

__device__ __forceinline__ u16 f2bf(float f) {
  unsigned u = __builtin_bit_cast(unsigned, f);
  u += 0x7fffu + ((u >> 16) & 1u);
  return (u16)(u >> 16);
}
__device__ __forceinline__ float bf2f(u16 h) {
  unsigned u = ((unsigned)h) << 16;
  return __builtin_bit_cast(float, u);
}
__device__ __forceinline__ void gload16(void* lds, const void* g) {
  __builtin_amdgcn_global_load_lds(
      (const __attribute__((address_space(1))) void*)g,
      (__attribute__((address_space(3))) void*)lds, 16, 0, 0);
}
__device__ __forceinline__ f32x4 mfma16(bf16x8 a, bf16x8 b, f32x4 c) {
  return __builtin_amdgcn_mfma_f32_16x16x32_bf16(a, b, c, 0, 0, 0);
}
__device__ __forceinline__ f32x16 mfma32(bf16x8 a, bf16x8 b, f32x16 c) {
  return __builtin_amdgcn_mfma_f32_32x32x16_bf16(a, b, c, 0, 0, 0);
}
// native 1-instruction transcendentals (exp2f/1.0f/x go through OCML's
// multi-instruction guarded sequences without fast-math; v_exp_f32/v_rcp_f32
// are 1-ulp -- far inside the bf16 tolerance)
__device__ __forceinline__ float nexp2(float x) { return __builtin_amdgcn_exp2f(x); }
__device__ __forceinline__ float nrcp(float x) { return __builtin_amdgcn_rcpf(x); }

// Load-balance table: (xcd parity -> 64 ranked (h<<4|qt) items, descending
// per-block iteration count). Slot c pairs with slot 63-c on the same CU.
// Ranking invariant under uniform window-margin scaling (monotone).
__device__ __constant__ unsigned char LB_TBL[128] = {
    // group A, ranks 0..63
    0x00,0x10,0x40,0x41,0x70,0x71,0x72,0x73,0x74,0x75,0x76,0x77,0x78,0x79,0x7A,
    0x01,0x11,0x42,0x7B,0x02,0x12,0x43,0x7C,0x03,0x13,0x44,0x7D,0x04,0x14,0x45,
    0x7E,0x05,0x15,0x46,0x7F,0x06,0x16,0x47,0x07,0x17,0x48,0x08,0x18,0x49,0x09,
    0x19,0x4A,0x0A,0x1A,0x4B,0x0B,0x1B,0x4C,0x0C,0x1C,0x4D,0x0D,0x1D,0x4E,0x0E,
    0x1E,0x4F,0x0F,0x1F,
    // group B, ranks 0..63
    0x20,0x30,0x31,0x50,0x51,0x52,0x53,0x60,0x61,0x62,0x63,0x64,0x65,
    0x21,0x32,0x54,0x66,0x22,0x33,0x55,0x67,0x23,0x34,0x56,0x68,0x24,0x35,0x57,
    0x69,0x25,0x36,0x58,0x6A,0x26,0x37,0x59,0x6B,0x27,0x38,0x5A,0x6C,0x28,0x39,
    0x5B,0x6D,0x29,0x3A,0x5C,0x6E,0x2A,0x3B,0x5D,0x6F,0x2B,0x3C,0x5E,0x2C,0x3D,
    0x5F,0x2D,0x3E,0x2E,0x3F,0x2F};

// ---------------- fused prep: converts (x, qkv_w, proj_w) + sincos --------
__global__ __launch_bounds__(256) void prep_kernel(const float* __restrict__ x,
                                                   const float* __restrict__ qkv_w,
                                                   const float* __restrict__ proj_w,
                                                   u16* __restrict__ XB,
                                                   u16* __restrict__ WQB,
                                                   u16* __restrict__ WPB,
                                                   float* __restrict__ sc) {
  const int bid = blockIdx.x, t = threadIdx.x;
  if (bid < 5120) {
    const float* src;
    u16* dst;
    size_t base;
    if (bid < 4096) { src = x; dst = XB; base = (size_t)bid; }
    else if (bid < 4864) { src = qkv_w; dst = WQB; base = (size_t)(bid - 4096); }
    else { src = proj_w; dst = WPB; base = (size_t)(bid - 4864); }
    size_t i = base * 256 + t;
    f32x4 v = *(const f32x4*)(src + i * 4);
    u16x4 o;
#pragma unroll
    for (int j = 0; j < 4; ++j) o[j] = f2bf(v[j]);
    *(u16x4*)(dst + i * 4) = o;
  } else {
    int i = (bid - 5120) * 256 + t;  // 2048*32
    int n = i >> 5, d = i & 31;
    float inv = powf(10000.0f, -(float)d * (1.0f / 32.0f));
    float f = (float)n * inv;
    sc[(size_t)n * 64 + d] = sinf(f);
    sc[(size_t)n * 64 + 32 + d] = cosf(f);
  }
}

// ---------------- GEMM C = A @ B^T (both row-major, K contiguous) ----------
// BK=32, 4 waves, double-buffered prefetch, XCD-clustered 1D grid.
// MODE 2: 128x128 tile, NB=12, fused RoPE epilogue (natural Q/K layout).
// MODE 0: 128x64 tile, NB=8 -> 512 blocks = 2 blocks/CU; f32 out + bias.
template <int MODE>
__global__ __launch_bounds__(256) void gemm_bt(const u16* __restrict__ A,
                                               const u16* __restrict__ Bw,
                                               float* __restrict__ Cout,
                                               const float* __restrict__ bias,
                                               const float* __restrict__ SC,
                                               u16* __restrict__ Qo,
                                               u16* __restrict__ Ko,
                                               u16* __restrict__ Vo,
                                               int M, int Nout, int K) {
  constexpr int NB = (MODE == 2) ? 12 : 8;    // N-blocks per M-panel
  constexpr int BN = (MODE == 2) ? 128 : 64;  // tile N
  constexpr int NJ = BN / 32;                 // per-wave j-frags (4 or 2)
  __shared__ u16 lA[2][128 * 32];
  __shared__ u16 lB[2][BN * 32];
  const int t = threadIdx.x;
  const int l = t & 63, w = t >> 6;
  const int lrow = l & 15, lg = l >> 4;
  const int id = blockIdx.x;
  const int xcd = id & 7, kk = id >> 3;
  const int m0 = ((kk / NB) * 8 + xcd) * 128;
  const int n0 = (kk % NB) * BN;
  const int wr = (w >> 1) * 64, wc = (w & 1) * (BN / 2);
  f32x4 acc[4][NJ];
#pragma unroll
  for (int i = 0; i < 4; ++i)
#pragma unroll
    for (int j = 0; j < NJ; ++j)
#pragma unroll
      for (int r = 0; r < 4; ++r) acc[i][j][r] = 0.f;

  const int srow = t >> 2;
  const int scb = (t & 3) * 16;
  const int nk = K >> 5;

  auto stageg = [&](int buf, int kt) {
#pragma unroll
    for (int c = 0; c < 2; ++c) {
      int row = c * 64 + srow;
      const char* ga = (const char*)A + ((size_t)(m0 + row) * K + kt * 32) * 2 + scb;
      gload16((char*)&lA[buf][0] + c * 4096 + t * 16, ga);
    }
#pragma unroll
    for (int c = 0; c < BN / 64; ++c) {
      int row = c * 64 + srow;
      const char* gb = (const char*)Bw + ((size_t)(n0 + row) * K + kt * 32) * 2 + scb;
      gload16((char*)&lB[buf][0] + c * 4096 + t * 16, gb);
    }
  };

  stageg(0, 0);
  __syncthreads();
  int cb = 0;
  for (int kt = 0; kt < nk; ++kt) {
    if (kt + 1 < nk) stageg(cb ^ 1, kt + 1);
    bf16x8 af[4], bfr[NJ];
#pragma unroll
    for (int i = 0; i < 4; ++i)
      af[i] = *(const bf16x8*)((const char*)&lA[cb][0] + (wr + i * 16 + lrow) * 64 + lg * 16);
#pragma unroll
    for (int j = 0; j < NJ; ++j)
      bfr[j] = *(const bf16x8*)((const char*)&lB[cb][0] + (wc + j * 16 + lrow) * 64 + lg * 16);
#pragma unroll
    for (int i = 0; i < 4; ++i)
#pragma unroll
      for (int j = 0; j < NJ; ++j)
        acc[i][j] = mfma16(af[i], bfr[j], acc[i][j]);
    __syncthreads();
    cb ^= 1;
  }

  if constexpr (MODE == 0) {
#pragma unroll
    for (int i = 0; i < 4; ++i)
#pragma unroll
      for (int j = 0; j < NJ; ++j)
#pragma unroll
        for (int r = 0; r < 4; ++r) {
          int m = m0 + wr + i * 16 + lg * 4 + r;
          int n = n0 + wc + j * 16 + lrow;
          Cout[(size_t)m * Nout + n] = acc[i][j][r] + bias[n];
        }
  } else {
    const int part = n0 >> 9;
    if (part < 2) {
      u16* Dst = (part == 0) ? Qo : Ko;
      const int hh = ((n0 & 511) + wc) >> 6;
#pragma unroll
      for (int i = 0; i < 4; ++i) {
#pragma unroll
        for (int r = 0; r < 4; ++r) {
          int m = m0 + wr + i * 16 + lg * 4 + r;
          int bb = m >> 11, nseq = m & 2047;
          const float* scrow = SC + (size_t)nseq * 64;
          u16* orow = Dst + ((size_t)(bb * 8 + hh) * 2048 + nseq) * 64;
#pragma unroll
          for (int j = 0; j < 2; ++j) {
            int dlo = j * 16 + lrow;
            float s = scrow[dlo], c = scrow[32 + dlo];
            float v1 = acc[i][j][r], v2 = acc[i][j + 2][r];
            orow[dlo] = f2bf(v1 * c - v2 * s);
            orow[dlo + 32] = f2bf(v2 * c + v1 * s);
          }
        }
      }
    } else {
#pragma unroll
      for (int i = 0; i < 4; ++i) {
        int m = m0 + wr + i * 16 + lg * 4;
        int bb = m >> 11, nseq = m & 2047;
#pragma unroll
        for (int j = 0; j < 4; ++j) {
          int pc = (n0 & 511) + wc + j * 16 + lrow;
          int hh = pc >> 6, d = pc & 63;
          u16x4 pk;
#pragma unroll
          for (int r = 0; r < 4; ++r) pk[r] = f2bf(acc[i][j][r]);
          *(u16x4*)(Vo + ((size_t)((bb * 8 + hh) * 64 + d)) * 2048 + nseq) = pk;
        }
      }
    }
  }
}

// ---------------- flash attention, ALiBi, dynamic-window split-KV ---------
// R9/R12 structure (frozen). This round's single change: window margin
// 60 -> 52 exp2-units. Dropped-mass bound 2^(41-M): M=52 -> 5e-4 relative
// worst case (score-range +-15 assumed; real range ~+-9 makes it ~2^-24),
// output error << remaining absmax budget (0.031). wint = M*2^(h-2)/log2e.
__global__ __launch_bounds__(512, 4) void attn_kernel(const u16* __restrict__ Q,
                                                      const u16* __restrict__ Kn,
                                                      const u16* __restrict__ Vt,
                                                      u16* __restrict__ Ob) {
  __shared__ u16 KV[2][2][2][4096];  // [buf][half][K/V][64 rows x 128B] = 64KB
  const int t = threadIdx.x, l = t & 63, w = t >> 6;
  const int li = l & 31, hi = l >> 5;
  const int half = w >> 2, g = w & 3;

  // table-driven placement
  const int id = blockIdx.x + 32 * blockIdx.y;
  const int xcd = id & 7, slot = id >> 3;
  const int rank = slot < 32 ? slot : 95 - slot;
  const int item = LB_TBL[(xcd & 1) * 64 + rank];
  const int h = item >> 4, qt = item & 15;
  const int bh = (xcd >> 1) * 8 + h;
  const int b = xcd >> 1;

  const int qg = qt * 128 + g * 32 + li;            // this lane's query
  const float sl2 = nexp2((float)(2 - h)) * LOG2E;  // MAX_BIAS*slope*log2e
  const float sc2 = 0.125f * LOG2E;                 // scale*log2e
  const int swz = (li & 7) << 4;

  // dynamic active range (block-uniform); margin M=52 exp2-units
  const int wint = (int)(9.0114f * (float)(1 << h));  // 52/sl2 window keys
  int lo_i = 128 * qt + 64 - wint;
  const int lo = lo_i <= 0 ? 0 : (lo_i & ~63);
  const int T = (2048 - lo) >> 6;
  const int nIter = (T + 1) >> 1;

  // Q fragments: qa[s] = Q[qg][d = s*16 + hi*8 + 0..7]
  bf16x8 qa[4];
  {
    const char* qb = (const char*)Q + ((size_t)bh * 2048 + qg) * 128 + hi * 16;
#pragma unroll
    for (int s = 0; s < 4; ++s) qa[s] = *(const bf16x8*)(qb + s * 32);
  }
  // ALiBi: key = k0 + kb*32 + 8*(r>>2) + (r&3) + 4*hi
  float cst[4];
#pragma unroll
  for (int j = 0; j < 4; ++j) cst[j] = (float)j * sl2;
  const float c8 = 8.f * sl2, c32 = 32.f * sl2;
  float vbm = (float)(4 * hi - qg) * sl2;  // (4hi - qg)*sl2 - shift (shift=0)
  float negm = 0.f;                        // -shift
  float lrun = 0.f;
  f32x16 oacc0, oacc1;
#pragma unroll
  for (int r = 0; r < 16; ++r) { oacc0[r] = 0.f; oacc1[r] = 0.f; }

  // stage both halves' tiles for iteration it: 32KB, 512 thr x 4 x 16B
  auto stage = [&](int buf, int it) {
#pragma unroll
    for (int c = 0; c < 4; ++c) {
      int o = c * 512 + t;               // chunk 0..2047
      int half_s = o >> 10, rem = o & 1023;
      int kv = rem >> 9, idx = rem & 511;
      int row = idx >> 3;
      int sb = ((idx & 7) * 16) ^ ((row & 7) << 4);
      int k0s = lo + (half_s ? nIter + it : it) * 64;
      if (k0s < 2048) {
        char* dst = (char*)KV + buf * 32768 + half_s * 16384 + kv * 8192 + idx * 16;
        const char* src;
        if (kv == 0)
          src = (const char*)Kn + ((size_t)(bh * 2048 + k0s + row)) * 128 + sb;
        else
          src = (const char*)Vt + ((size_t)(bh * 64 + row)) * 4096 +
                (size_t)k0s * 2 + sb;
        gload16(dst, src);
      }
    }
  };

  stage(0, 0);
  __syncthreads();
  int cur = 0;
  const char* myK = (const char*)KV + half * 16384;
  const char* myV = myK + 8192;
  for (int it = 0; it < nIter; ++it) {
    if (it + 1 < nIter) stage(cur ^ 1, it + 1);  // prefetch next tile pair

    const int k0g = lo + (half ? nIter + it : it) * 64;
    const bool active = (k0g < 2048);  // wave-uniform (odd-T tail only)
    if (active) {
      const float basem0 = fmaf((float)k0g, sl2, vbm);

      // ---- per-kb: S' = K Q^T -> bias -> exp2 -> P-frag (16 live) ----
      float ls0 = 0.f, ls1 = 0.f;
      bf16x8 pf[4];
#pragma unroll
      for (int kb = 0; kb < 2; ++kb) {
        f32x16 sa;
#pragma unroll
        for (int r = 0; r < 16; ++r) sa[r] = 0.f;
        const char* kb_base = myK + cur * 32768 + kb * 4096 + li * 128;
        __builtin_amdgcn_s_setprio(1);
#pragma unroll
        for (int s = 0; s < 4; ++s) {
          bf16x8 kf = *(const bf16x8*)(kb_base + ((s * 32 + hi * 16) ^ swz));
          sa = mfma32(kf, qa[s], sa);
        }
        __builtin_amdgcn_s_setprio(0);
        float bq[4];
        bq[0] = kb ? basem0 + c32 : basem0;
        bq[1] = bq[0] + c8;
        bq[2] = bq[1] + c8;
        bq[3] = bq[2] + c8;
        float p[16];
#pragma unroll
        for (int r = 0; r < 16; ++r)
          p[r] = fmaf(sa[r], sc2, fminf(bq[r >> 2] + cst[r & 3], negm));
#pragma unroll
        for (int r = 0; r < 16; r += 2) {
          float e0 = nexp2(p[r]), e1 = nexp2(p[r + 1]);
          p[r] = e0;
          p[r + 1] = e1;
          ls0 += e0;
          ls1 += e1;
        }
        // P -> bf16 A-fragments via cvt_pk + permlane32_swap (T12)
#pragma unroll
        for (int s = 0; s < 2; ++s) {
          u32 a0, b0, a1, b1;
          asm("v_cvt_pk_bf16_f32 %0, %1, %2" : "=v"(a0) : "v"(p[s * 8 + 0]), "v"(p[s * 8 + 1]));
          asm("v_cvt_pk_bf16_f32 %0, %1, %2" : "=v"(b0) : "v"(p[s * 8 + 4]), "v"(p[s * 8 + 5]));
          asm("v_cvt_pk_bf16_f32 %0, %1, %2" : "=v"(a1) : "v"(p[s * 8 + 2]), "v"(p[s * 8 + 3]));
          asm("v_cvt_pk_bf16_f32 %0, %1, %2" : "=v"(b1) : "v"(p[s * 8 + 6]), "v"(p[s * 8 + 7]));
          asm("v_permlane32_swap_b32 %0, %1" : "+v"(a0), "+v"(b0));
          asm("v_permlane32_swap_b32 %0, %1" : "+v"(a1), "+v"(b1));
          u32x4 fr;
          fr[0] = a0; fr[1] = a1; fr[2] = b0; fr[3] = b1;
          pf[kb * 2 + s] = __builtin_bit_cast(bf16x8, fr);
        }
      }
      float ls = ls0 + ls1;
      ls += __shfl_xor(ls, 32);
      lrun += ls;

      // ---- O' += Vt P^T (2 d-blocks x 4 k-steps) ----
      const char* vb_base = myV + cur * 32768 + li * 128;
      __builtin_amdgcn_s_setprio(1);
#pragma unroll
      for (int ks = 0; ks < 4; ++ks) {
        int off = (ks * 32 + hi * 16) ^ swz;
        bf16x8 vf0 = *(const bf16x8*)(vb_base + off);
        bf16x8 vf1 = *(const bf16x8*)(vb_base + 4096 + off);
        oacc0 = mfma32(vf0, pf[ks], oacc0);
        oacc1 = mfma32(vf1, pf[ks], oacc1);
      }
      __builtin_amdgcn_s_setprio(0);

      // overflow guard (never taken for this data; exact shift if it fires)
      if (__any(lrun > 1e28f)) {
        vbm -= 64.f;
        negm -= 64.f;
        lrun *= 0x1p-64f;
#pragma unroll
        for (int r = 0; r < 16; ++r) {
          oacc0[r] *= 0x1p-64f;
          oacc1[r] *= 0x1p-64f;
        }
      }
    }
    __syncthreads();
    cur ^= 1;
  }

  // ---- merge halves: wave w+4 publishes, wave w combines ----
  float* S = (float*)KV;  // reuse staging LDS: [g][34][64] f32
  if (half == 1) {
    float* base = S + (size_t)g * 34 * 64;
#pragma unroll
    for (int r = 0; r < 16; ++r) {
      base[r * 64 + l] = oacc0[r];
      base[(16 + r) * 64 + l] = oacc1[r];
    }
    base[32 * 64 + l] = lrun;
    base[33 * 64 + l] = negm;
  }
  __syncthreads();
  if (half == 0) {
    const float* base = S + (size_t)g * 34 * 64;
    float lB = base[32 * 64 + l];
    float negmB = base[33 * 64 + l];
    float mA = -negm, mB = -negmB;
    float mS = fmaxf(mA, mB);
    float aA = nexp2(mA - mS), aB = nexp2(mB - mS);
    float linv = nrcp(fmaf(lrun, aA, lB * aB));
    float cA = aA * linv, cB = aB * linv;
    u16* orow = Ob + ((size_t)b * 2048 + qg) * 512 + h * 64;
#pragma unroll
    for (int db = 0; db < 2; ++db) {
#pragma unroll
      for (int gg = 0; gg < 4; ++gg) {
        u16x4 pk;
#pragma unroll
        for (int j = 0; j < 4; ++j) {
          int r = gg * 4 + j;
          float oA = db ? oacc1[r] : oacc0[r];
          float oB = base[(db * 16 + r) * 64 + l];
          pk[j] = f2bf(oA * cA + oB * cB);
        }
        *(u16x4*)(orow + db * 32 + gg * 8 + 4 * hi) = pk;
      }
    }
  }
}

// ---------------- launch ---------------------------------------------------
extern "C" void kernel_launch(void* const* d_in, const int* in_sizes, int n_in,
                              void* d_out, int out_size, void* d_ws, size_t ws_size,
                              hipStream_t stream) {
  const float* x = (const float*)d_in[0];
  const float* qkv_w = (const float*)d_in[1];
  const float* proj_w = (const float*)d_in[2];
  const float* proj_b = (const float*)d_in[3];
  char* ws = (char*)d_ws;

  u16* XB = (u16*)(ws + 0);             // 8192x512 bf16 (x)
  u16* WQB = (u16*)(ws + 8388608);      // 1536x512 bf16 (qkv_w)
  u16* WPB = (u16*)(ws + 9961472);      // 512x512 bf16 (proj_w)
  u16* QB = (u16*)(ws + 10485760);      // [32][2048][64] (roped q)
  u16* KB = (u16*)(ws + 18874368);      // [32][2048][64] (roped k)
  u16* VTB = (u16*)(ws + 27262976);     // [32][64][2048] (v transposed)
  u16* OB = (u16*)(ws + 35651584);      // 8192x512 bf16 (attn out)
  float* SC = (float*)(ws + 44040192);  // 2048x64 f32 sin/cos

  prep_kernel<<<5376, 256, 0, stream>>>(x, qkv_w, proj_w, XB, WQB, WPB, SC);
  gemm_bt<2><<<768, 256, 0, stream>>>(XB, WQB, nullptr, nullptr, SC, QB,
                                      KB, VTB, 8192, 1536, 512);
  attn_kernel<<<dim3(32, 16), 512, 0, stream>>>(QB, KB, VTB, OB);
  gemm_bt<0><<<512, 256, 0, stream>>>(OB, WPB, (float*)d_out, proj_b,
                                      nullptr, nullptr, nullptr, nullptr,
                                      8192, 512, 512);
}

// Round 17
// 83.126 us; speedup vs baseline: 1.1753x; 1.0208x over previous
//
#include <hip/hip_runtime.h>

typedef unsigned short u16;
typedef unsigned int u32;
typedef __attribute__((ext_vector_type(8))) __bf16 bf16x8;
typedef __attribute__((ext_vector_type(4))) float f32x4;
typedef __attribute__((ext_vector_type(16))) float f32x16;
typedef __attribute__((ext_vector_type(4))) u16 u16x4;
typedef __attribute__((ext_vector_type(4))) u32 u32x4;

#define LOG2E 1.44269504088896f

__device__ __forceinline__ u16 f2bf(float f) {
  unsigned u = __builtin_bit_cast(unsigned, f);
  u += 0x7fffu + ((u >> 16) & 1u);
  return (u16)(u >> 16);
}
__device__ __forceinline__ float bf2f(u16 h) {
  unsigned u = ((unsigned)h) << 16;
  return __builtin_bit_cast(float, u);
}
__device__ __forceinline__ void gload16(void* lds, const void* g) {
  __builtin_amdgcn_global_load_lds(
      (const __attribute__((address_space(1))) void*)g,
      (__attribute__((address_space(3))) void*)lds, 16, 0, 0);
}
__device__ __forceinline__ f32x4 mfma16(bf16x8 a, bf16x8 b, f32x4 c) {
  return __builtin_amdgcn_mfma_f32_16x16x32_bf16(a, b, c, 0, 0, 0);
}
__device__ __forceinline__ f32x16 mfma32(bf16x8 a, bf16x8 b, f32x16 c) {
  return __builtin_amdgcn_mfma_f32_32x32x16_bf16(a, b, c, 0, 0, 0);
}
// native 1-instruction transcendentals (exp2f/1.0f/x go through OCML's
// multi-instruction guarded sequences without fast-math; v_exp_f32/v_rcp_f32
// are 1-ulp -- far inside the bf16 tolerance)
__device__ __forceinline__ float nexp2(float x) { return __builtin_amdgcn_exp2f(x); }
__device__ __forceinline__ float nrcp(float x) { return __builtin_amdgcn_rcpf(x); }

// Load-balance table: (xcd parity -> 64 ranked (h<<4|qt) items, descending
// per-block iteration count). Slot c pairs with slot 63-c on the same CU.
__device__ __constant__ unsigned char LB_TBL[128] = {
    // group A, ranks 0..63
    0x00,0x10,0x40,0x41,0x70,0x71,0x72,0x73,0x74,0x75,0x76,0x77,0x78,0x79,0x7A,
    0x01,0x11,0x42,0x7B,0x02,0x12,0x43,0x7C,0x03,0x13,0x44,0x7D,0x04,0x14,0x45,
    0x7E,0x05,0x15,0x46,0x7F,0x06,0x16,0x47,0x07,0x17,0x48,0x08,0x18,0x49,0x09,
    0x19,0x4A,0x0A,0x1A,0x4B,0x0B,0x1B,0x4C,0x0C,0x1C,0x4D,0x0D,0x1D,0x4E,0x0E,
    0x1E,0x4F,0x0F,0x1F,
    // group B, ranks 0..63
    0x20,0x30,0x31,0x50,0x51,0x52,0x53,0x60,0x61,0x62,0x63,0x64,0x65,
    0x21,0x32,0x54,0x66,0x22,0x33,0x55,0x67,0x23,0x34,0x56,0x68,0x24,0x35,0x57,
    0x69,0x25,0x36,0x58,0x6A,0x26,0x37,0x59,0x6B,0x27,0x38,0x5A,0x6C,0x28,0x39,
    0x5B,0x6D,0x29,0x3A,0x5C,0x6E,0x2A,0x3B,0x5D,0x6F,0x2B,0x3C,0x5E,0x2C,0x3D,
    0x5F,0x2D,0x3E,0x2E,0x3F,0x2F};

// ---------------- fused prep: converts (x, qkv_w, proj_w) + sincos --------
__global__ __launch_bounds__(256) void prep_kernel(const float* __restrict__ x,
                                                   const float* __restrict__ qkv_w,
                                                   const float* __restrict__ proj_w,
                                                   u16* __restrict__ XB,
                                                   u16* __restrict__ WQB,
                                                   u16* __restrict__ WPB,
                                                   float* __restrict__ sc) {
  const int bid = blockIdx.x, t = threadIdx.x;
  if (bid < 5120) {
    const float* src;
    u16* dst;
    size_t base;
    if (bid < 4096) { src = x; dst = XB; base = (size_t)bid; }
    else if (bid < 4864) { src = qkv_w; dst = WQB; base = (size_t)(bid - 4096); }
    else { src = proj_w; dst = WPB; base = (size_t)(bid - 4864); }
    size_t i = base * 256 + t;
    f32x4 v = *(const f32x4*)(src + i * 4);
    u16x4 o;
#pragma unroll
    for (int j = 0; j < 4; ++j) o[j] = f2bf(v[j]);
    *(u16x4*)(dst + i * 4) = o;
  } else {
    int i = (bid - 5120) * 256 + t;  // 2048*32
    int n = i >> 5, d = i & 31;
    float inv = powf(10000.0f, -(float)d * (1.0f / 32.0f));
    float f = (float)n * inv;
    sc[(size_t)n * 64 + d] = sinf(f);
    sc[(size_t)n * 64 + 32 + d] = cosf(f);
  }
}

// ---------------- GEMM C = A @ B^T (both row-major, K contiguous) ----------
// BK=32, 4 waves (2x2), double-buffered prefetch, XCD-clustered 1D grid.
// Per-wave output = (BM/2)x(BN/2) -> WI=BM/32 i-frags, WJ=BN/32 j-frags
// (R16 bug: WI=BM/64 left half the rows unwritten -- fixed).
// MODE 2: 128x128, NB=12, WI=WJ=4, fused RoPE epilogue (unchanged behavior).
// MODE 0: 64x64, NB=8 -> 1024 blocks = 4 blocks/CU, WI=WJ=2; f32 out + bias.
template <int MODE>
__global__ __launch_bounds__(256) void gemm_bt(const u16* __restrict__ A,
                                               const u16* __restrict__ Bw,
                                               float* __restrict__ Cout,
                                               const float* __restrict__ bias,
                                               const float* __restrict__ SC,
                                               u16* __restrict__ Qo,
                                               u16* __restrict__ Ko,
                                               u16* __restrict__ Vo,
                                               int M, int Nout, int K) {
  constexpr int NB = (MODE == 2) ? 12 : 8;    // N-blocks per M-panel
  constexpr int BM = (MODE == 2) ? 128 : 64;  // tile M
  constexpr int BN = (MODE == 2) ? 128 : 64;  // tile N
  constexpr int WI = BM / 32;                 // per-wave i-frags (4 or 2)
  constexpr int WJ = BN / 32;                 // per-wave j-frags (4 or 2)
  __shared__ u16 lA[2][BM * 32];
  __shared__ u16 lB[2][BN * 32];
  const int t = threadIdx.x;
  const int l = t & 63, w = t >> 6;
  const int lrow = l & 15, lg = l >> 4;
  const int id = blockIdx.x;
  const int xcd = id & 7, kk = id >> 3;
  const int m0 = ((kk / NB) * 8 + xcd) * BM;
  const int n0 = (kk % NB) * BN;
  const int wr = (w >> 1) * (BM / 2), wc = (w & 1) * (BN / 2);
  f32x4 acc[WI][WJ];
#pragma unroll
  for (int i = 0; i < WI; ++i)
#pragma unroll
    for (int j = 0; j < WJ; ++j)
#pragma unroll
      for (int r = 0; r < 4; ++r) acc[i][j][r] = 0.f;

  const int srow = t >> 2;
  const int scb = (t & 3) * 16;
  const int nk = K >> 5;

  auto stageg = [&](int buf, int kt) {
#pragma unroll
    for (int c = 0; c < BM / 64; ++c) {
      int row = c * 64 + srow;
      const char* ga = (const char*)A + ((size_t)(m0 + row) * K + kt * 32) * 2 + scb;
      gload16((char*)&lA[buf][0] + c * 4096 + t * 16, ga);
    }
#pragma unroll
    for (int c = 0; c < BN / 64; ++c) {
      int row = c * 64 + srow;
      const char* gb = (const char*)Bw + ((size_t)(n0 + row) * K + kt * 32) * 2 + scb;
      gload16((char*)&lB[buf][0] + c * 4096 + t * 16, gb);
    }
  };

  stageg(0, 0);
  __syncthreads();
  int cb = 0;
  for (int kt = 0; kt < nk; ++kt) {
    if (kt + 1 < nk) stageg(cb ^ 1, kt + 1);
    bf16x8 af[WI], bfr[WJ];
#pragma unroll
    for (int i = 0; i < WI; ++i)
      af[i] = *(const bf16x8*)((const char*)&lA[cb][0] + (wr + i * 16 + lrow) * 64 + lg * 16);
#pragma unroll
    for (int j = 0; j < WJ; ++j)
      bfr[j] = *(const bf16x8*)((const char*)&lB[cb][0] + (wc + j * 16 + lrow) * 64 + lg * 16);
#pragma unroll
    for (int i = 0; i < WI; ++i)
#pragma unroll
      for (int j = 0; j < WJ; ++j)
        acc[i][j] = mfma16(af[i], bfr[j], acc[i][j]);
    __syncthreads();
    cb ^= 1;
  }

  if constexpr (MODE == 0) {
#pragma unroll
    for (int i = 0; i < WI; ++i)
#pragma unroll
      for (int j = 0; j < WJ; ++j)
#pragma unroll
        for (int r = 0; r < 4; ++r) {
          int m = m0 + wr + i * 16 + lg * 4 + r;
          int n = n0 + wc + j * 16 + lrow;
          Cout[(size_t)m * Nout + n] = acc[i][j][r] + bias[n];
        }
  } else {
    const int part = n0 >> 9;
    if (part < 2) {
      u16* Dst = (part == 0) ? Qo : Ko;
      const int hh = ((n0 & 511) + wc) >> 6;
#pragma unroll
      for (int i = 0; i < 4; ++i) {
#pragma unroll
        for (int r = 0; r < 4; ++r) {
          int m = m0 + wr + i * 16 + lg * 4 + r;
          int bb = m >> 11, nseq = m & 2047;
          const float* scrow = SC + (size_t)nseq * 64;
          u16* orow = Dst + ((size_t)(bb * 8 + hh) * 2048 + nseq) * 64;
#pragma unroll
          for (int j = 0; j < 2; ++j) {
            int dlo = j * 16 + lrow;
            float s = scrow[dlo], c = scrow[32 + dlo];
            float v1 = acc[i][j][r], v2 = acc[i][j + 2][r];
            orow[dlo] = f2bf(v1 * c - v2 * s);
            orow[dlo + 32] = f2bf(v2 * c + v1 * s);
          }
        }
      }
    } else {
#pragma unroll
      for (int i = 0; i < 4; ++i) {
        int m = m0 + wr + i * 16 + lg * 4;
        int bb = m >> 11, nseq = m & 2047;
#pragma unroll
        for (int j = 0; j < 4; ++j) {
          int pc = (n0 & 511) + wc + j * 16 + lrow;
          int hh = pc >> 6, d = pc & 63;
          u16x4 pk;
#pragma unroll
          for (int r = 0; r < 4; ++r) pk[r] = f2bf(acc[i][j][r]);
          *(u16x4*)(Vo + ((size_t)((bb * 8 + hh) * 64 + d)) * 2048 + nseq) = pk;
        }
      }
    }
  }
}

// ---------------- flash attention, ALiBi, dynamic-window split-KV ---------
// FROZEN: R9/R12 structure + M=52 window margin (R15-measured-good, 42.3 us).
// Do not add loop-carried pointer state or branchy bias paths (spill at the
// (512,4) cap -- R10/R11 regressions).
__global__ __launch_bounds__(512, 4) void attn_kernel(const u16* __restrict__ Q,
                                                      const u16* __restrict__ Kn,
                                                      const u16* __restrict__ Vt,
                                                      u16* __restrict__ Ob) {
  __shared__ u16 KV[2][2][2][4096];  // [buf][half][K/V][64 rows x 128B] = 64KB
  const int t = threadIdx.x, l = t & 63, w = t >> 6;
  const int li = l & 31, hi = l >> 5;
  const int half = w >> 2, g = w & 3;

  // table-driven placement
  const int id = blockIdx.x + 32 * blockIdx.y;
  const int xcd = id & 7, slot = id >> 3;
  const int rank = slot < 32 ? slot : 95 - slot;
  const int item = LB_TBL[(xcd & 1) * 64 + rank];
  const int h = item >> 4, qt = item & 15;
  const int bh = (xcd >> 1) * 8 + h;
  const int b = xcd >> 1;

  const int qg = qt * 128 + g * 32 + li;            // this lane's query
  const float sl2 = nexp2((float)(2 - h)) * LOG2E;  // MAX_BIAS*slope*log2e
  const float sc2 = 0.125f * LOG2E;                 // scale*log2e
  const int swz = (li & 7) << 4;

  // dynamic active range (block-uniform); margin M=52 exp2-units
  const int wint = (int)(9.0114f * (float)(1 << h));  // 52/sl2 window keys
  int lo_i = 128 * qt + 64 - wint;
  const int lo = lo_i <= 0 ? 0 : (lo_i & ~63);
  const int T = (2048 - lo) >> 6;
  const int nIter = (T + 1) >> 1;

  // Q fragments: qa[s] = Q[qg][d = s*16 + hi*8 + 0..7]
  bf16x8 qa[4];
  {
    const char* qb = (const char*)Q + ((size_t)bh * 2048 + qg) * 128 + hi * 16;
#pragma unroll
    for (int s = 0; s < 4; ++s) qa[s] = *(const bf16x8*)(qb + s * 32);
  }
  // ALiBi: key = k0 + kb*32 + 8*(r>>2) + (r&3) + 4*hi
  float cst[4];
#pragma unroll
  for (int j = 0; j < 4; ++j) cst[j] = (float)j * sl2;
  const float c8 = 8.f * sl2, c32 = 32.f * sl2;
  float vbm = (float)(4 * hi - qg) * sl2;  // (4hi - qg)*sl2 - shift (shift=0)
  float negm = 0.f;                        // -shift
  float lrun = 0.f;
  f32x16 oacc0, oacc1;
#pragma unroll
  for (int r = 0; r < 16; ++r) { oacc0[r] = 0.f; oacc1[r] = 0.f; }

  // stage both halves' tiles for iteration it: 32KB, 512 thr x 4 x 16B
  auto stage = [&](int buf, int it) {
#pragma unroll
    for (int c = 0; c < 4; ++c) {
      int o = c * 512 + t;               // chunk 0..2047
      int half_s = o >> 10, rem = o & 1023;
      int kv = rem >> 9, idx = rem & 511;
      int row = idx >> 3;
      int sb = ((idx & 7) * 16) ^ ((row & 7) << 4);
      int k0s = lo + (half_s ? nIter + it : it) * 64;
      if (k0s < 2048) {
        char* dst = (char*)KV + buf * 32768 + half_s * 16384 + kv * 8192 + idx * 16;
        const char* src;
        if (kv == 0)
          src = (const char*)Kn + ((size_t)(bh * 2048 + k0s + row)) * 128 + sb;
        else
          src = (const char*)Vt + ((size_t)(bh * 64 + row)) * 4096 +
                (size_t)k0s * 2 + sb;
        gload16(dst, src);
      }
    }
  };

  stage(0, 0);
  __syncthreads();
  int cur = 0;
  const char* myK = (const char*)KV + half * 16384;
  const char* myV = myK + 8192;
  for (int it = 0; it < nIter; ++it) {
    if (it + 1 < nIter) stage(cur ^ 1, it + 1);  // prefetch next tile pair

    const int k0g = lo + (half ? nIter + it : it) * 64;
    const bool active = (k0g < 2048);  // wave-uniform (odd-T tail only)
    if (active) {
      const float basem0 = fmaf((float)k0g, sl2, vbm);

      // ---- per-kb: S' = K Q^T -> bias -> exp2 -> P-frag (16 live) ----
      float ls0 = 0.f, ls1 = 0.f;
      bf16x8 pf[4];
#pragma unroll
      for (int kb = 0; kb < 2; ++kb) {
        f32x16 sa;
#pragma unroll
        for (int r = 0; r < 16; ++r) sa[r] = 0.f;
        const char* kb_base = myK + cur * 32768 + kb * 4096 + li * 128;
        __builtin_amdgcn_s_setprio(1);
#pragma unroll
        for (int s = 0; s < 4; ++s) {
          bf16x8 kf = *(const bf16x8*)(kb_base + ((s * 32 + hi * 16) ^ swz));
          sa = mfma32(kf, qa[s], sa);
        }
        __builtin_amdgcn_s_setprio(0);
        float bq[4];
        bq[0] = kb ? basem0 + c32 : basem0;
        bq[1] = bq[0] + c8;
        bq[2] = bq[1] + c8;
        bq[3] = bq[2] + c8;
        float p[16];
#pragma unroll
        for (int r = 0; r < 16; ++r)
          p[r] = fmaf(sa[r], sc2, fminf(bq[r >> 2] + cst[r & 3], negm));
#pragma unroll
        for (int r = 0; r < 16; r += 2) {
          float e0 = nexp2(p[r]), e1 = nexp2(p[r + 1]);
          p[r] = e0;
          p[r + 1] = e1;
          ls0 += e0;
          ls1 += e1;
        }
        // P -> bf16 A-fragments via cvt_pk + permlane32_swap (T12)
#pragma unroll
        for (int s = 0; s < 2; ++s) {
          u32 a0, b0, a1, b1;
          asm("v_cvt_pk_bf16_f32 %0, %1, %2" : "=v"(a0) : "v"(p[s * 8 + 0]), "v"(p[s * 8 + 1]));
          asm("v_cvt_pk_bf16_f32 %0, %1, %2" : "=v"(b0) : "v"(p[s * 8 + 4]), "v"(p[s * 8 + 5]));
          asm("v_cvt_pk_bf16_f32 %0, %1, %2" : "=v"(a1) : "v"(p[s * 8 + 2]), "v"(p[s * 8 + 3]));
          asm("v_cvt_pk_bf16_f32 %0, %1, %2" : "=v"(b1) : "v"(p[s * 8 + 6]), "v"(p[s * 8 + 7]));
          asm("v_permlane32_swap_b32 %0, %1" : "+v"(a0), "+v"(b0));
          asm("v_permlane32_swap_b32 %0, %1" : "+v"(a1), "+v"(b1));
          u32x4 fr;
          fr[0] = a0; fr[1] = a1; fr[2] = b0; fr[3] = b1;
          pf[kb * 2 + s] = __builtin_bit_cast(bf16x8, fr);
        }
      }
      float ls = ls0 + ls1;
      ls += __shfl_xor(ls, 32);
      lrun += ls;

      // ---- O' += Vt P^T (2 d-blocks x 4 k-steps) ----
      const char* vb_base = myV + cur * 32768 + li * 128;
      __builtin_amdgcn_s_setprio(1);
#pragma unroll
      for (int ks = 0; ks < 4; ++ks) {
        int off = (ks * 32 + hi * 16) ^ swz;
        bf16x8 vf0 = *(const bf16x8*)(vb_base + off);
        bf16x8 vf1 = *(const bf16x8*)(vb_base + 4096 + off);
        oacc0 = mfma32(vf0, pf[ks], oacc0);
        oacc1 = mfma32(vf1, pf[ks], oacc1);
      }
      __builtin_amdgcn_s_setprio(0);

      // overflow guard (never taken for this data; exact shift if it fires)
      if (__any(lrun > 1e28f)) {
        vbm -= 64.f;
        negm -= 64.f;
        lrun *= 0x1p-64f;
#pragma unroll
        for (int r = 0; r < 16; ++r) {
          oacc0[r] *= 0x1p-64f;
          oacc1[r] *= 0x1p-64f;
        }
      }
    }
    __syncthreads();
    cur ^= 1;
  }

  // ---- merge halves: wave w+4 publishes, wave w combines ----
  float* S = (float*)KV;  // reuse staging LDS: [g][34][64] f32
  if (half == 1) {
    float* base = S + (size_t)g * 34 * 64;
#pragma unroll
    for (int r = 0; r < 16; ++r) {
      base[r * 64 + l] = oacc0[r];
      base[(16 + r) * 64 + l] = oacc1[r];
    }
    base[32 * 64 + l] = lrun;
    base[33 * 64 + l] = negm;
  }
  __syncthreads();
  if (half == 0) {
    const float* base = S + (size_t)g * 34 * 64;
    float lB = base[32 * 64 + l];
    float negmB = base[33 * 64 + l];
    float mA = -negm, mB = -negmB;
    float mS = fmaxf(mA, mB);
    float aA = nexp2(mA - mS), aB = nexp2(mB - mS);
    float linv = nrcp(fmaf(lrun, aA, lB * aB));
    float cA = aA * linv, cB = aB * linv;
    u16* orow = Ob + ((size_t)b * 2048 + qg) * 512 + h * 64;
#pragma unroll
    for (int db = 0; db < 2; ++db) {
#pragma unroll
      for (int gg = 0; gg < 4; ++gg) {
        u16x4 pk;
#pragma unroll
        for (int j = 0; j < 4; ++j) {
          int r = gg * 4 + j;
          float oA = db ? oacc1[r] : oacc0[r];
          float oB = base[(db * 16 + r) * 64 + l];
          pk[j] = f2bf(oA * cA + oB * cB);
        }
        *(u16x4*)(orow + db * 32 + gg * 8 + 4 * hi) = pk;
      }
    }
  }
}

// ---------------- launch ---------------------------------------------------
extern "C" void kernel_launch(void* const* d_in, const int* in_sizes, int n_in,
                              void* d_out, int out_size, void* d_ws, size_t ws_size,
                              hipStream_t stream) {
  const float* x = (const float*)d_in[0];
  const float* qkv_w = (const float*)d_in[1];
  const float* proj_w = (const float*)d_in[2];
  const float* proj_b = (const float*)d_in[3];
  char* ws = (char*)d_ws;

  u16* XB = (u16*)(ws + 0);             // 8192x512 bf16 (x)
  u16* WQB = (u16*)(ws + 8388608);      // 1536x512 bf16 (qkv_w)
  u16* WPB = (u16*)(ws + 9961472);      // 512x512 bf16 (proj_w)
  u16* QB = (u16*)(ws + 10485760);      // [32][2048][64] (roped q)
  u16* KB = (u16*)(ws + 18874368);      // [32][2048][64] (roped k)
  u16* VTB = (u16*)(ws + 27262976);     // [32][64][2048] (v transposed)
  u16* OB = (u16*)(ws + 35651584);      // 8192x512 bf16 (attn out)
  float* SC = (float*)(ws + 44040192);  // 2048x64 f32 sin/cos

  prep_kernel<<<5376, 256, 0, stream>>>(x, qkv_w, proj_w, XB, WQB, WPB, SC);
  gemm_bt<2><<<768, 256, 0, stream>>>(XB, WQB, nullptr, nullptr, SC, QB,
                                      KB, VTB, 8192, 1536, 512);
  attn_kernel<<<dim3(32, 16), 512, 0, stream>>>(QB, KB, VTB, OB);
  gemm_bt<0><<<1024, 256, 0, stream>>>(OB, WPB, (float*)d_out, proj_b,
                                       nullptr, nullptr, nullptr, nullptr,
                                       8192, 512, 512);
}